// Round 4
// baseline (2369.186 us; speedup 1.0000x reference)
//
#include <hip/hip_runtime.h>
#include <math.h>

#define HH 96
#define WW 128
#define DD 64
#define BB 8
#define KK 7
#define CC 32
#define HWSZ (HH*WW)
#define EPSF 1e-8f
#define TILES (HWSZ/256)     // 48
#define ND 8                 // depths per thread (4 pairs)
#define DG (DD/ND)           // 8

static __device__ __forceinline__ float bf_lo(unsigned u){ return __uint_as_float(u << 16); }
static __device__ __forceinline__ float bf_hi(unsigned u){ return __uint_as_float(u & 0xffff0000u); }
static __device__ __forceinline__ unsigned f2bf(float f){
    unsigned u = __float_as_uint(f);
    return (u + 0x7fffu + ((u >> 16) & 1u)) >> 16;   // RNE
}

// ---------- pack src: (B*K, C, HW) fp32 -> (B*K, HW, C) bf16 ----------
__global__ __launch_bounds__(256) void pack_src(const float* __restrict__ in,
                                                unsigned short* __restrict__ outT)
{
    __shared__ float t[CC][33];
    int blk    = blockIdx.x;
    int hwTile = blk % (HWSZ/32);
    int v      = blk / (HWSZ/32);
    int hw0    = hwTile*32;
    const float* ip = in + (size_t)v*CC*HWSZ;
    unsigned short* op = outT + (size_t)v*HWSZ*CC;
    int j = threadIdx.x & 31;
    int r = threadIdx.x >> 5;
    #pragma unroll
    for (int i = 0; i < 4; ++i) {
        int c = r + i*8;
        t[c][j] = ip[(size_t)c*HWSZ + hw0 + j];
    }
    __syncthreads();
    int row = threadIdx.x >> 3;
    int cg  = threadIdx.x & 7;
    int c0  = cg*4;
    float f0 = t[c0+0][row], f1 = t[c0+1][row];
    float f2 = t[c0+2][row], f3 = t[c0+3][row];
    unsigned u0 = (f2bf(f1) << 16) | f2bf(f0);
    unsigned u1 = (f2bf(f3) << 16) | f2bf(f2);
    *reinterpret_cast<uint2*>(op + (size_t)(hw0+row)*CC + c0) = make_uint2(u0, u1);
}

// ---------- pack cur: (B, C, HW) fp32 -> (B, HW, C) fp32 ----------
__global__ __launch_bounds__(256) void pack_cur(const float* __restrict__ in,
                                                float* __restrict__ outT)
{
    __shared__ float t[CC][33];
    int blk    = blockIdx.x;
    int hwTile = blk % (HWSZ/32);
    int v      = blk / (HWSZ/32);
    int hw0    = hwTile*32;
    const float* ip = in + (size_t)v*CC*HWSZ;
    float*       op = outT + (size_t)v*HWSZ*CC;
    int j = threadIdx.x & 31;
    int r = threadIdx.x >> 5;
    #pragma unroll
    for (int i = 0; i < 4; ++i) {
        int c = r + i*8;
        t[c][j] = ip[(size_t)c*HWSZ + hw0 + j];
    }
    __syncthreads();
    int row = threadIdx.x >> 3;
    int cg  = threadIdx.x & 7;
    int c0  = cg*4;
    float4 f = make_float4(t[c0+0][row], t[c0+1][row], t[c0+2][row], t[c0+3][row]);
    *reinterpret_cast<float4*>(op + (size_t)(hw0+row)*CC + c0) = f;
}

// ---------- per-depth projection result ----------
struct Tap {
    unsigned o0, o1, o2, o3;   // byte offsets into src slice
    float w0, w1, w2, w3;      // bilinear weights * validity * (z>0)
};

static __device__ __forceinline__ Tap project(float depth, float q0, float q1, float q2,
                                              float m3, float m7, float m11)
{
    float cam0 = fmaf(depth, q0, m3);
    float cam1 = fmaf(depth, q1, m7);
    float zraw = fmaf(depth, q2, m11);
    float z     = zraw + EPSF;
    float scale = (fabsf(zraw) > EPSF) ? (1.f / z) : 1.f;
    float x = cam0 * scale - 0.5f;
    float y = cam1 * scale - 0.5f;
    float x0f = floorf(x), y0f = floorf(y);
    float wx1 = x - x0f,  wy1 = y - y0f;
    float wx0 = 1.f - wx1, wy0 = 1.f - wy1;
    bool vx0 = (x0f >= 0.f)       && (x0f <= (float)(WW-1));
    bool vx1 = (x0f + 1.f >= 0.f) && (x0f + 1.f <= (float)(WW-1));
    bool vy0 = (y0f >= 0.f)       && (y0f <= (float)(HH-1));
    bool vy1 = (y0f + 1.f >= 0.f) && (y0f + 1.f <= (float)(HH-1));
    float zm = (z > 0.f) ? 1.f : 0.f;
    Tap t;
    t.w0 = (vx0 && vy0) ? wx0*wy0*zm : 0.f;
    t.w1 = (vx1 && vy0) ? wx1*wy0*zm : 0.f;
    t.w2 = (vx0 && vy1) ? wx0*wy1*zm : 0.f;
    t.w3 = (vx1 && vy1) ? wx1*wy1*zm : 0.f;
    int ix0 = (int)fminf(fmaxf(x0f,       0.f), (float)(WW-1));
    int ix1 = (int)fminf(fmaxf(x0f + 1.f, 0.f), (float)(WW-1));
    int iy0 = (int)fminf(fmaxf(y0f,       0.f), (float)(HH-1));
    int iy1 = (int)fminf(fmaxf(y0f + 1.f, 0.f), (float)(HH-1));
    t.o0 = (unsigned)(iy0*WW + ix0) * (CC*2);   // bf16: 64B per pixel
    t.o1 = (unsigned)(iy0*WW + ix1) * (CC*2);
    t.o2 = (unsigned)(iy1*WW + ix0) * (CC*2);
    t.o3 = (unsigned)(iy1*WW + ix1) * (CC*2);
    return t;
}

#define TAP_FMA(A, V, cc) \
    A = fmaf(curv[(cc)*8+0], bf_lo((V).x), A); A = fmaf(curv[(cc)*8+1], bf_hi((V).x), A); \
    A = fmaf(curv[(cc)*8+2], bf_lo((V).y), A); A = fmaf(curv[(cc)*8+3], bf_hi((V).y), A); \
    A = fmaf(curv[(cc)*8+4], bf_lo((V).z), A); A = fmaf(curv[(cc)*8+5], bf_hi((V).z), A); \
    A = fmaf(curv[(cc)*8+6], bf_lo((V).w), A); A = fmaf(curv[(cc)*8+7], bf_hi((V).w), A);

// ---------- main: bf16-NHWC gather, 8 depths/thread as 4 pairs ----------
__global__ __launch_bounds__(256, 4) void cv_packed(
    const float* __restrict__ curT,          // (B, HW, C) fp32
    const unsigned short* __restrict__ srcT, // (B, K, HW, C) bf16
    const float* __restrict__ Emat,
    const float* __restrict__ Kmat,
    const float* __restrict__ invK,
    const float* __restrict__ mnp,
    const float* __restrict__ mxp,
    float* __restrict__ out)
{
    // natural order (round-2 style): tile fastest -> tiles spread across XCDs,
    // consecutive depth-groups reuse each XCD's resident source region.
    int blk  = blockIdx.x;
    int tile = blk % TILES;
    int r    = blk / TILES;
    int g    = r % DG;
    int b    = r / DG;

    __shared__ float sM[KK][12];
    if (threadIdx.x < KK) {
        int k = threadIdx.x;
        const float* Km = Kmat + (size_t)(b*KK + k)*16;
        const float* Em = Emat + (size_t)(b*KK + k)*16;
        float P[3][4];
        #pragma unroll
        for (int i = 0; i < 3; ++i)
            #pragma unroll
            for (int jj = 0; jj < 4; ++jj) {
                float s = 0.f;
                #pragma unroll
                for (int l = 0; l < 4; ++l) s = fmaf(Km[i*4+l], Em[l*4+jj], s);
                P[i][jj] = s;
            }
        const float* iK = invK + (size_t)b*16;
        #pragma unroll
        for (int i = 0; i < 3; ++i) {
            #pragma unroll
            for (int jj = 0; jj < 3; ++jj) {
                float s = 0.f;
                #pragma unroll
                for (int l = 0; l < 3; ++l) s = fmaf(P[i][l], iK[l*4+jj], s);
                sM[k][i*4+jj] = s;
            }
            sM[k][i*4+3] = P[i][3];
        }
    }
    __syncthreads();

    int p  = tile*256 + threadIdx.x;
    float fx = (float)(p & (WW-1)) + 0.5f;
    float fy = (float)(p >> 7) + 0.5f;

    float curv[CC];
    {
        const float4* cp = reinterpret_cast<const float4*>(curT + ((size_t)b*HWSZ + p)*CC);
        #pragma unroll
        for (int i = 0; i < 8; ++i) {
            float4 f = cp[i];
            curv[4*i+0] = f.x; curv[4*i+1] = f.y; curv[4*i+2] = f.z; curv[4*i+3] = f.w;
        }
    }

    float mnb = mnp[b];
    float lmn = logf(mnb);
    float lr  = logf(mxp[b] / mnb);
    float depths[ND];
    #pragma unroll
    for (int dd = 0; dd < ND; ++dd)
        depths[dd] = expf(fmaf(lr, (float)(g*ND + dd) * (1.f/63.f), lmn));

    float acc[ND];
    #pragma unroll
    for (int dd = 0; dd < ND; ++dd) acc[dd] = 0.f;

    for (int k = 0; k < KK; ++k) {
        float q0 = fmaf(sM[k][0], fx, fmaf(sM[k][1], fy, sM[k][2]));
        float q1 = fmaf(sM[k][4], fx, fmaf(sM[k][5], fy, sM[k][6]));
        float q2 = fmaf(sM[k][8], fx, fmaf(sM[k][9], fy, sM[k][10]));
        float m3 = sM[k][3], m7 = sM[k][7], m11 = sM[k][11];

        const char* sbb = reinterpret_cast<const char*>(srcT + (size_t)(b*KK + k)*HWSZ*CC);

        // 4 depth-pairs; pair 0 misses to L2/L3, pairs 1..3 mostly hit L1
        #pragma unroll
        for (int pp = 0; pp < ND/2; ++pp) {
            Tap A = project(depths[2*pp+0], q0, q1, q2, m3, m7, m11);
            Tap B = project(depths[2*pp+1], q0, q1, q2, m3, m7, m11);

            float a0=0.f,a1=0.f,a2=0.f,a3=0.f,a4=0.f,a5=0.f,a6=0.f,a7=0.f;
            #pragma unroll
            for (int cc = 0; cc < 4; ++cc) {
                uint4 v0 = *reinterpret_cast<const uint4*>(sbb + A.o0 + cc*16);
                uint4 v1 = *reinterpret_cast<const uint4*>(sbb + A.o1 + cc*16);
                uint4 v2 = *reinterpret_cast<const uint4*>(sbb + A.o2 + cc*16);
                uint4 v3 = *reinterpret_cast<const uint4*>(sbb + A.o3 + cc*16);
                uint4 v4 = *reinterpret_cast<const uint4*>(sbb + B.o0 + cc*16);
                uint4 v5 = *reinterpret_cast<const uint4*>(sbb + B.o1 + cc*16);
                uint4 v6 = *reinterpret_cast<const uint4*>(sbb + B.o2 + cc*16);
                uint4 v7 = *reinterpret_cast<const uint4*>(sbb + B.o3 + cc*16);
                TAP_FMA(a0, v0, cc)  TAP_FMA(a1, v1, cc)
                TAP_FMA(a2, v2, cc)  TAP_FMA(a3, v3, cc)
                TAP_FMA(a4, v4, cc)  TAP_FMA(a5, v5, cc)
                TAP_FMA(a6, v6, cc)  TAP_FMA(a7, v7, cc)
            }
            acc[2*pp+0] += A.w0*a0 + A.w1*a1 + A.w2*a2 + A.w3*a3;
            acc[2*pp+1] += B.w0*a4 + B.w1*a5 + B.w2*a6 + B.w3*a7;
        }
    }

    #pragma unroll
    for (int dd = 0; dd < ND; ++dd)
        out[(size_t)(b*DD + g*ND + dd)*HWSZ + p] = acc[dd];
}

// ---------- fallback (ws too small): round-1 style, known correct ----------
__global__ __launch_bounds__(256) void cv_fallback(
    const float* __restrict__ cur, const float* __restrict__ src,
    const float* __restrict__ Emat, const float* __restrict__ Kmat,
    const float* __restrict__ invK, const float* __restrict__ mnp,
    const float* __restrict__ mxp, float* __restrict__ out)
{
    int blk  = blockIdx.x;
    int tile = blk % TILES;
    int bd   = blk / TILES;
    int d    = bd % DD;
    int b    = bd / DD;
    __shared__ float sM[KK][12];
    __shared__ float sDepth;
    if (threadIdx.x < KK) {
        int k = threadIdx.x;
        const float* Km = Kmat + (size_t)(b*KK + k)*16;
        const float* Em = Emat + (size_t)(b*KK + k)*16;
        float P[3][4];
        #pragma unroll
        for (int i = 0; i < 3; ++i)
            #pragma unroll
            for (int jj = 0; jj < 4; ++jj) {
                float s = 0.f;
                #pragma unroll
                for (int l = 0; l < 4; ++l) s = fmaf(Km[i*4+l], Em[l*4+jj], s);
                P[i][jj] = s;
            }
        const float* iK = invK + (size_t)b*16;
        #pragma unroll
        for (int i = 0; i < 3; ++i) {
            #pragma unroll
            for (int jj = 0; jj < 3; ++jj) {
                float s = 0.f;
                #pragma unroll
                for (int l = 0; l < 3; ++l) s = fmaf(P[i][l], iK[l*4+jj], s);
                sM[k][i*4+jj] = s;
            }
            sM[k][i*4+3] = P[i][3];
        }
    }
    if (threadIdx.x == KK) {
        float mnb = mnp[b], mxb = mxp[b];
        sDepth = expf(logf(mnb) + logf(mxb/mnb) * ((float)d * (1.f/63.f)));
    }
    __syncthreads();
    int p  = tile*256 + threadIdx.x;
    float fx = (float)(p & (WW-1)) + 0.5f;
    float fy = (float)(p >> 7) + 0.5f;
    float depth = sDepth;
    float curv[CC];
    const float* curp = cur + (size_t)b*CC*HWSZ + p;
    #pragma unroll
    for (int c = 0; c < CC; ++c) curv[c] = curp[(size_t)c*HWSZ];
    float acc = 0.f;
    for (int k = 0; k < KK; ++k) {
        float q0 = fmaf(sM[k][0], fx, fmaf(sM[k][1], fy, sM[k][2]));
        float q1 = fmaf(sM[k][4], fx, fmaf(sM[k][5], fy, sM[k][6]));
        float q2 = fmaf(sM[k][8], fx, fmaf(sM[k][9], fy, sM[k][10]));
        Tap t = project(depth, q0, q1, q2, sM[k][3], sM[k][7], sM[k][11]);
        const float* sb = src + (size_t)(b*KK + k)*CC*HWSZ;
        int o0 = (int)(t.o0/(CC*2)), o1 = (int)(t.o1/(CC*2));
        int o2 = (int)(t.o2/(CC*2)), o3 = (int)(t.o3/(CC*2));
        float a0=0.f,a1=0.f,a2=0.f,a3=0.f;
        #pragma unroll 8
        for (int c = 0; c < CC; ++c) {
            const float* sc = sb + (size_t)c*HWSZ;
            a0 = fmaf(curv[c], sc[o0], a0);
            a1 = fmaf(curv[c], sc[o1], a1);
            a2 = fmaf(curv[c], sc[o2], a2);
            a3 = fmaf(curv[c], sc[o3], a3);
        }
        acc += t.w0*a0 + t.w1*a1 + t.w2*a2 + t.w3*a3;
    }
    out[(size_t)(b*DD + d)*HWSZ + p] = acc;
}

extern "C" void kernel_launch(void* const* d_in, const int* in_sizes, int n_in,
                              void* d_out, int out_size, void* d_ws, size_t ws_size,
                              hipStream_t stream) {
    const float* cur   = (const float*)d_in[0];
    const float* srcf  = (const float*)d_in[1];
    const float* Emat  = (const float*)d_in[2];
    const float* Kmat  = (const float*)d_in[3];
    const float* invK  = (const float*)d_in[4];
    const float* mn    = (const float*)d_in[5];
    const float* mx    = (const float*)d_in[6];
    float* out = (float*)d_out;

    const size_t srcT_bytes = (size_t)BB*KK*HWSZ*CC*2;          // 44 MB bf16
    const size_t curT_bytes = (size_t)BB*HWSZ*CC*4;             // 12.6 MB fp32
    dim3 block(256);

    if (ws_size >= srcT_bytes + curT_bytes) {
        unsigned short* srcT = (unsigned short*)d_ws;
        float* curT = (float*)((char*)d_ws + srcT_bytes);
        pack_src<<<dim3(BB*KK*(HWSZ/32)), block, 0, stream>>>(srcf, srcT);
        pack_cur<<<dim3(BB*(HWSZ/32)),   block, 0, stream>>>(cur, curT);
        cv_packed<<<dim3(BB*DG*TILES), block, 0, stream>>>(curT, srcT, Emat, Kmat, invK, mn, mx, out);
    } else {
        cv_fallback<<<dim3(BB*DD*TILES), block, 0, stream>>>(cur, srcf, Emat, Kmat, invK, mn, mx, out);
    }
}

// Round 5
// 2171.252 us; speedup vs baseline: 1.0912x; 1.0912x over previous
//
#include <hip/hip_runtime.h>
#include <math.h>

#define HH 96
#define WW 128
#define DD 64
#define BB 8
#define KK 7
#define CC 32
#define HWSZ (HH*WW)
#define EPSF 1e-8f
#define TILES (HWSZ/256)     // 48
#define ND 16                // depths per thread (8 pairs), k-outer d-inner
#define DG (DD/ND)           // 4

static __device__ __forceinline__ float bf_lo(unsigned u){ return __uint_as_float(u << 16); }
static __device__ __forceinline__ float bf_hi(unsigned u){ return __uint_as_float(u & 0xffff0000u); }
static __device__ __forceinline__ unsigned f2bf(float f){
    unsigned u = __float_as_uint(f);
    return (u + 0x7fffu + ((u >> 16) & 1u)) >> 16;   // RNE
}

// ---------- pack src: (B*K, C, HW) fp32 -> (B*K, HW, C) bf16 ----------
__global__ __launch_bounds__(256) void pack_src(const float* __restrict__ in,
                                                unsigned short* __restrict__ outT)
{
    __shared__ float t[CC][33];
    int blk    = blockIdx.x;
    int hwTile = blk % (HWSZ/32);
    int v      = blk / (HWSZ/32);
    int hw0    = hwTile*32;
    const float* ip = in + (size_t)v*CC*HWSZ;
    unsigned short* op = outT + (size_t)v*HWSZ*CC;
    int j = threadIdx.x & 31;
    int r = threadIdx.x >> 5;
    #pragma unroll
    for (int i = 0; i < 4; ++i) {
        int c = r + i*8;
        t[c][j] = ip[(size_t)c*HWSZ + hw0 + j];
    }
    __syncthreads();
    int row = threadIdx.x >> 3;
    int cg  = threadIdx.x & 7;
    int c0  = cg*4;
    float f0 = t[c0+0][row], f1 = t[c0+1][row];
    float f2 = t[c0+2][row], f3 = t[c0+3][row];
    unsigned u0 = (f2bf(f1) << 16) | f2bf(f0);
    unsigned u1 = (f2bf(f3) << 16) | f2bf(f2);
    *reinterpret_cast<uint2*>(op + (size_t)(hw0+row)*CC + c0) = make_uint2(u0, u1);
}

// ---------- pack cur: (B, C, HW) fp32 -> (B, HW, C) fp32 ----------
__global__ __launch_bounds__(256) void pack_cur(const float* __restrict__ in,
                                                float* __restrict__ outT)
{
    __shared__ float t[CC][33];
    int blk    = blockIdx.x;
    int hwTile = blk % (HWSZ/32);
    int v      = blk / (HWSZ/32);
    int hw0    = hwTile*32;
    const float* ip = in + (size_t)v*CC*HWSZ;
    float*       op = outT + (size_t)v*HWSZ*CC;
    int j = threadIdx.x & 31;
    int r = threadIdx.x >> 5;
    #pragma unroll
    for (int i = 0; i < 4; ++i) {
        int c = r + i*8;
        t[c][j] = ip[(size_t)c*HWSZ + hw0 + j];
    }
    __syncthreads();
    int row = threadIdx.x >> 3;
    int cg  = threadIdx.x & 7;
    int c0  = cg*4;
    float4 f = make_float4(t[c0+0][row], t[c0+1][row], t[c0+2][row], t[c0+3][row]);
    *reinterpret_cast<float4*>(op + (size_t)(hw0+row)*CC + c0) = f;
}

// ---------- per-depth projection result ----------
struct Tap {
    unsigned o0, o1, o2, o3;   // byte offsets into src slice
    float w0, w1, w2, w3;      // bilinear weights * validity * (z>0)
};

static __device__ __forceinline__ Tap project(float depth, float q0, float q1, float q2,
                                              float m3, float m7, float m11)
{
    float cam0 = fmaf(depth, q0, m3);
    float cam1 = fmaf(depth, q1, m7);
    float zraw = fmaf(depth, q2, m11);
    float z     = zraw + EPSF;
    float scale = (fabsf(zraw) > EPSF) ? (1.f / z) : 1.f;
    float x = cam0 * scale - 0.5f;
    float y = cam1 * scale - 0.5f;
    float x0f = floorf(x), y0f = floorf(y);
    float wx1 = x - x0f,  wy1 = y - y0f;
    float wx0 = 1.f - wx1, wy0 = 1.f - wy1;
    bool vx0 = (x0f >= 0.f)       && (x0f <= (float)(WW-1));
    bool vx1 = (x0f + 1.f >= 0.f) && (x0f + 1.f <= (float)(WW-1));
    bool vy0 = (y0f >= 0.f)       && (y0f <= (float)(HH-1));
    bool vy1 = (y0f + 1.f >= 0.f) && (y0f + 1.f <= (float)(HH-1));
    float zm = (z > 0.f) ? 1.f : 0.f;
    Tap t;
    t.w0 = (vx0 && vy0) ? wx0*wy0*zm : 0.f;
    t.w1 = (vx1 && vy0) ? wx1*wy0*zm : 0.f;
    t.w2 = (vx0 && vy1) ? wx0*wy1*zm : 0.f;
    t.w3 = (vx1 && vy1) ? wx1*wy1*zm : 0.f;
    int ix0 = (int)fminf(fmaxf(x0f,       0.f), (float)(WW-1));
    int ix1 = (int)fminf(fmaxf(x0f + 1.f, 0.f), (float)(WW-1));
    int iy0 = (int)fminf(fmaxf(y0f,       0.f), (float)(HH-1));
    int iy1 = (int)fminf(fmaxf(y0f + 1.f, 0.f), (float)(HH-1));
    t.o0 = (unsigned)(iy0*WW + ix0) * (CC*2);   // bf16: 64B per pixel
    t.o1 = (unsigned)(iy0*WW + ix1) * (CC*2);
    t.o2 = (unsigned)(iy1*WW + ix0) * (CC*2);
    t.o3 = (unsigned)(iy1*WW + ix1) * (CC*2);
    return t;
}

#define TAP_FMA(A, V, cc) \
    A = fmaf(curv[(cc)*8+0], bf_lo((V).x), A); A = fmaf(curv[(cc)*8+1], bf_hi((V).x), A); \
    A = fmaf(curv[(cc)*8+2], bf_lo((V).y), A); A = fmaf(curv[(cc)*8+3], bf_hi((V).y), A); \
    A = fmaf(curv[(cc)*8+4], bf_lo((V).z), A); A = fmaf(curv[(cc)*8+5], bf_hi((V).z), A); \
    A = fmaf(curv[(cc)*8+6], bf_lo((V).w), A); A = fmaf(curv[(cc)*8+7], bf_hi((V).w), A);

// ---------- main: k-outer, 16 depths/thread (8 pairs), b pinned to XCD ----------
__global__ __launch_bounds__(256, 4) void cv_packed(
    const float* __restrict__ curT,          // (B, HW, C) fp32
    const unsigned short* __restrict__ srcT, // (B, K, HW, C) bf16
    const float* __restrict__ Emat,
    const float* __restrict__ Kmat,
    const float* __restrict__ invK,
    const float* __restrict__ mnp,
    const float* __restrict__ mxp,
    float* __restrict__ out)
{
    // blk = b + 8*(tile + TILES*g): b -> XCD pin (round-robin dispatch),
    // tile next-fastest so same-b blocks on an XCD share overlapping bands.
    int blk  = blockIdx.x;
    int b    = blk & 7;
    int r    = blk >> 3;
    int tile = r % TILES;
    int g    = r / TILES;

    __shared__ float sM[KK][12];
    if (threadIdx.x < KK) {
        int k = threadIdx.x;
        const float* Km = Kmat + (size_t)(b*KK + k)*16;
        const float* Em = Emat + (size_t)(b*KK + k)*16;
        float P[3][4];
        #pragma unroll
        for (int i = 0; i < 3; ++i)
            #pragma unroll
            for (int jj = 0; jj < 4; ++jj) {
                float s = 0.f;
                #pragma unroll
                for (int l = 0; l < 4; ++l) s = fmaf(Km[i*4+l], Em[l*4+jj], s);
                P[i][jj] = s;
            }
        const float* iK = invK + (size_t)b*16;
        #pragma unroll
        for (int i = 0; i < 3; ++i) {
            #pragma unroll
            for (int jj = 0; jj < 3; ++jj) {
                float s = 0.f;
                #pragma unroll
                for (int l = 0; l < 3; ++l) s = fmaf(P[i][l], iK[l*4+jj], s);
                sM[k][i*4+jj] = s;
            }
            sM[k][i*4+3] = P[i][3];
        }
    }
    __syncthreads();

    int p  = tile*256 + threadIdx.x;
    float fx = (float)(p & (WW-1)) + 0.5f;
    float fy = (float)(p >> 7) + 0.5f;

    float curv[CC];
    {
        const float4* cp = reinterpret_cast<const float4*>(curT + ((size_t)b*HWSZ + p)*CC);
        #pragma unroll
        for (int i = 0; i < 8; ++i) {
            float4 f = cp[i];
            curv[4*i+0] = f.x; curv[4*i+1] = f.y; curv[4*i+2] = f.z; curv[4*i+3] = f.w;
        }
    }

    float mnb = mnp[b];
    float lmn = logf(mnb);
    float lr  = logf(mxp[b] / mnb);
    float depths[ND];
    #pragma unroll
    for (int dd = 0; dd < ND; ++dd)
        depths[dd] = expf(fmaf(lr, (float)(g*ND + dd) * (1.f/63.f), lmn));

    float acc[ND];
    #pragma unroll
    for (int dd = 0; dd < ND; ++dd) acc[dd] = 0.f;

    for (int k = 0; k < KK; ++k) {
        float q0 = fmaf(sM[k][0], fx, fmaf(sM[k][1], fy, sM[k][2]));
        float q1 = fmaf(sM[k][4], fx, fmaf(sM[k][5], fy, sM[k][6]));
        float q2 = fmaf(sM[k][8], fx, fmaf(sM[k][9], fy, sM[k][10]));
        float m3 = sM[k][3], m7 = sM[k][7], m11 = sM[k][11];

        const char* sbb = reinterpret_cast<const char*>(srcT + (size_t)(b*KK + k)*HWSZ*CC);

        // 8 depth-pairs: the tap band slides ~1px per step -> L2-resident reuse
        #pragma unroll
        for (int pp = 0; pp < ND/2; ++pp) {
            Tap A = project(depths[2*pp+0], q0, q1, q2, m3, m7, m11);
            Tap B = project(depths[2*pp+1], q0, q1, q2, m3, m7, m11);

            float a0=0.f,a1=0.f,a2=0.f,a3=0.f,a4=0.f,a5=0.f,a6=0.f,a7=0.f;
            #pragma unroll
            for (int cc = 0; cc < 4; ++cc) {
                uint4 v0 = *reinterpret_cast<const uint4*>(sbb + A.o0 + cc*16);
                uint4 v1 = *reinterpret_cast<const uint4*>(sbb + A.o1 + cc*16);
                uint4 v2 = *reinterpret_cast<const uint4*>(sbb + A.o2 + cc*16);
                uint4 v3 = *reinterpret_cast<const uint4*>(sbb + A.o3 + cc*16);
                uint4 v4 = *reinterpret_cast<const uint4*>(sbb + B.o0 + cc*16);
                uint4 v5 = *reinterpret_cast<const uint4*>(sbb + B.o1 + cc*16);
                uint4 v6 = *reinterpret_cast<const uint4*>(sbb + B.o2 + cc*16);
                uint4 v7 = *reinterpret_cast<const uint4*>(sbb + B.o3 + cc*16);
                TAP_FMA(a0, v0, cc)  TAP_FMA(a1, v1, cc)
                TAP_FMA(a2, v2, cc)  TAP_FMA(a3, v3, cc)
                TAP_FMA(a4, v4, cc)  TAP_FMA(a5, v5, cc)
                TAP_FMA(a6, v6, cc)  TAP_FMA(a7, v7, cc)
            }
            acc[2*pp+0] += A.w0*a0 + A.w1*a1 + A.w2*a2 + A.w3*a3;
            acc[2*pp+1] += B.w0*a4 + B.w1*a5 + B.w2*a6 + B.w3*a7;
        }
    }

    #pragma unroll
    for (int dd = 0; dd < ND; ++dd)
        out[(size_t)(b*DD + g*ND + dd)*HWSZ + p] = acc[dd];
}

// ---------- fallback (ws too small): round-1 style, known correct ----------
__global__ __launch_bounds__(256) void cv_fallback(
    const float* __restrict__ cur, const float* __restrict__ src,
    const float* __restrict__ Emat, const float* __restrict__ Kmat,
    const float* __restrict__ invK, const float* __restrict__ mnp,
    const float* __restrict__ mxp, float* __restrict__ out)
{
    int blk  = blockIdx.x;
    int tile = blk % TILES;
    int bd   = blk / TILES;
    int d    = bd % DD;
    int b    = bd / DD;
    __shared__ float sM[KK][12];
    __shared__ float sDepth;
    if (threadIdx.x < KK) {
        int k = threadIdx.x;
        const float* Km = Kmat + (size_t)(b*KK + k)*16;
        const float* Em = Emat + (size_t)(b*KK + k)*16;
        float P[3][4];
        #pragma unroll
        for (int i = 0; i < 3; ++i)
            #pragma unroll
            for (int jj = 0; jj < 4; ++jj) {
                float s = 0.f;
                #pragma unroll
                for (int l = 0; l < 4; ++l) s = fmaf(Km[i*4+l], Em[l*4+jj], s);
                P[i][jj] = s;
            }
        const float* iK = invK + (size_t)b*16;
        #pragma unroll
        for (int i = 0; i < 3; ++i) {
            #pragma unroll
            for (int jj = 0; jj < 3; ++jj) {
                float s = 0.f;
                #pragma unroll
                for (int l = 0; l < 3; ++l) s = fmaf(P[i][l], iK[l*4+jj], s);
                sM[k][i*4+jj] = s;
            }
            sM[k][i*4+3] = P[i][3];
        }
    }
    if (threadIdx.x == KK) {
        float mnb = mnp[b], mxb = mxp[b];
        sDepth = expf(logf(mnb) + logf(mxb/mnb) * ((float)d * (1.f/63.f)));
    }
    __syncthreads();
    int p  = tile*256 + threadIdx.x;
    float fx = (float)(p & (WW-1)) + 0.5f;
    float fy = (float)(p >> 7) + 0.5f;
    float depth = sDepth;
    float curv[CC];
    const float* curp = cur + (size_t)b*CC*HWSZ + p;
    #pragma unroll
    for (int c = 0; c < CC; ++c) curv[c] = curp[(size_t)c*HWSZ];
    float acc = 0.f;
    for (int k = 0; k < KK; ++k) {
        float q0 = fmaf(sM[k][0], fx, fmaf(sM[k][1], fy, sM[k][2]));
        float q1 = fmaf(sM[k][4], fx, fmaf(sM[k][5], fy, sM[k][6]));
        float q2 = fmaf(sM[k][8], fx, fmaf(sM[k][9], fy, sM[k][10]));
        Tap t = project(depth, q0, q1, q2, sM[k][3], sM[k][7], sM[k][11]);
        const float* sb = src + (size_t)(b*KK + k)*CC*HWSZ;
        int o0 = (int)(t.o0/(CC*2)), o1 = (int)(t.o1/(CC*2));
        int o2 = (int)(t.o2/(CC*2)), o3 = (int)(t.o3/(CC*2));
        float a0=0.f,a1=0.f,a2=0.f,a3=0.f;
        #pragma unroll 8
        for (int c = 0; c < CC; ++c) {
            const float* sc = sb + (size_t)c*HWSZ;
            a0 = fmaf(curv[c], sc[o0], a0);
            a1 = fmaf(curv[c], sc[o1], a1);
            a2 = fmaf(curv[c], sc[o2], a2);
            a3 = fmaf(curv[c], sc[o3], a3);
        }
        acc += t.w0*a0 + t.w1*a1 + t.w2*a2 + t.w3*a3;
    }
    out[(size_t)(b*DD + d)*HWSZ + p] = acc;
}

extern "C" void kernel_launch(void* const* d_in, const int* in_sizes, int n_in,
                              void* d_out, int out_size, void* d_ws, size_t ws_size,
                              hipStream_t stream) {
    const float* cur   = (const float*)d_in[0];
    const float* srcf  = (const float*)d_in[1];
    const float* Emat  = (const float*)d_in[2];
    const float* Kmat  = (const float*)d_in[3];
    const float* invK  = (const float*)d_in[4];
    const float* mn    = (const float*)d_in[5];
    const float* mx    = (const float*)d_in[6];
    float* out = (float*)d_out;

    const size_t srcT_bytes = (size_t)BB*KK*HWSZ*CC*2;          // 44 MB bf16
    const size_t curT_bytes = (size_t)BB*HWSZ*CC*4;             // 12.6 MB fp32
    dim3 block(256);

    if (ws_size >= srcT_bytes + curT_bytes) {
        unsigned short* srcT = (unsigned short*)d_ws;
        float* curT = (float*)((char*)d_ws + srcT_bytes);
        pack_src<<<dim3(BB*KK*(HWSZ/32)), block, 0, stream>>>(srcf, srcT);
        pack_cur<<<dim3(BB*(HWSZ/32)),   block, 0, stream>>>(cur, curT);
        cv_packed<<<dim3(BB*DG*TILES), block, 0, stream>>>(curT, srcT, Emat, Kmat, invK, mn, mx, out);
    } else {
        cv_fallback<<<dim3(BB*DD*TILES), block, 0, stream>>>(cur, srcf, Emat, Kmat, invK, mn, mx, out);
    }
}

// Round 6
// 974.308 us; speedup vs baseline: 2.4317x; 2.2285x over previous
//
#include <hip/hip_runtime.h>
#include <math.h>

#define HH 96
#define WW 128
#define DD 64
#define BB 8
#define KK 7
#define CC 32
#define HWSZ (HH*WW)
#define EPSF 1e-8f
#define NCH 16               // channel-pair chunks
#define NDT 32               // depths per thread (2 depth-groups per block)
#define PXT 256              // pixels per block tile
#define ROWB 520             // LDS row stride bytes (130 px * 4B) - 8B aligned, odd bank walk
#define BIAS 528             // pad before slice (covers iyb=-1, ixb=-1), 8B aligned
#define BUFB (BIAS + HH*ROWB + 528)    // 528 + 49920 + 528 = 50976 bytes
#define BUFW (BUFB/4)                  // 12744 u32

static __device__ __forceinline__ float bf_lo(unsigned u){ return __uint_as_float(u << 16); }
static __device__ __forceinline__ float bf_hi(unsigned u){ return __uint_as_float(u & 0xffff0000u); }
static __device__ __forceinline__ unsigned f2bf(float f){
    unsigned u = __float_as_uint(f);
    return (u + 0x7fffu + ((u >> 16) & 1u)) >> 16;   // RNE
}

// ---- pack src: (B*K, C, HW) f32 -> (B*K, 16, HW, 2ch) bf16-packed-u32 ----
__global__ __launch_bounds__(256) void pack_src2(const float* __restrict__ in,
                                                 unsigned* __restrict__ outP)
{
    int gid = blockIdx.x * 256 + threadIdx.x;          // (v,cc,px)
    int px  = gid % HWSZ;
    int rest = gid / HWSZ;
    int cc  = rest % NCH;
    int v   = rest / NCH;
    if (v >= BB*KK) return;
    const float* ip = in + (size_t)(v*CC + 2*cc)*HWSZ + px;
    float c0 = ip[0];
    float c1 = ip[HWSZ];
    outP[(size_t)(v*NCH + cc)*HWSZ + px] = (f2bf(c1) << 16) | f2bf(c0);
}

// ---- pack cur: (B, C, HW) f32 -> (B, 16, HW, 2ch) f32 pairs ----
__global__ __launch_bounds__(256) void pack_cur2(const float* __restrict__ in,
                                                 float2* __restrict__ outP)
{
    int gid = blockIdx.x * 256 + threadIdx.x;          // (b,cc,px)
    int px  = gid % HWSZ;
    int rest = gid / HWSZ;
    int cc  = rest % NCH;
    int b   = rest / NCH;
    if (b >= BB) return;
    const float* ip = in + (size_t)(b*CC + 2*cc)*HWSZ + px;
    outP[(size_t)(b*NCH + cc)*HWSZ + px] = make_float2(ip[0], ip[HWSZ]);
}

// ---- main: LDS-staged channel-sliced gather ----
__global__ __launch_bounds__(512, 2) void cv_lds(
    const float2* __restrict__ curP,     // (B,16,HW,2) f32
    const unsigned* __restrict__ srcC,   // (B,K,16,HW) u32 (2 bf16 ch)
    const float* __restrict__ Emat,
    const float* __restrict__ Kmat,
    const float* __restrict__ invK,
    const float* __restrict__ mnp,
    const float* __restrict__ mxp,
    float* __restrict__ out)
{
    __shared__ unsigned sbuf[BUFW];
    __shared__ float sM[KK][12];

    int blk  = blockIdx.x;
    int b    = blk & 7;           // XCD-pinned batch
    int tile = blk >> 3;          // 0..47
    int tid  = threadIdx.x;

    // zero LDS (pads + dummy cols must be exactly 0: junk*0 must stay 0)
    for (int i = tid; i < BUFW; i += 512) sbuf[i] = 0;

    if (tid < KK) {
        int k = tid;
        const float* Km = Kmat + (size_t)(b*KK + k)*16;
        const float* Em = Emat + (size_t)(b*KK + k)*16;
        float P[3][4];
        #pragma unroll
        for (int i = 0; i < 3; ++i)
            #pragma unroll
            for (int jj = 0; jj < 4; ++jj) {
                float s = 0.f;
                #pragma unroll
                for (int l = 0; l < 4; ++l) s = fmaf(Km[i*4+l], Em[l*4+jj], s);
                P[i][jj] = s;
            }
        const float* iK = invK + (size_t)b*16;
        #pragma unroll
        for (int i = 0; i < 3; ++i) {
            #pragma unroll
            for (int jj = 0; jj < 3; ++jj) {
                float s = 0.f;
                #pragma unroll
                for (int l = 0; l < 3; ++l) s = fmaf(P[i][l], iK[l*4+jj], s);
                sM[k][i*4+jj] = s;
            }
            sM[k][i*4+3] = P[i][3];
        }
    }
    __syncthreads();

    int p     = tile*PXT + (tid & 255);
    int dg    = tid >> 8;          // 0 or 1
    int dbase = dg * NDT;
    float fx = (float)(p & (WW-1)) + 0.5f;
    float fy = (float)(p >> 7) + 0.5f;

    float mnb = mnp[b];
    float lmn = logf(mnb);
    float lr  = logf(mxp[b] / mnb);

    float acc[NDT];
    #pragma unroll
    for (int d = 0; d < NDT; ++d) acc[d] = 0.f;

    unsigned offs[NDT], wA[NDT], wB[NDT];
    const char* bp = (const char*)sbuf;
    char* bpw = (char*)sbuf;

    for (int k = 0; k < KK; ++k) {
        float q0 = fmaf(sM[k][0], fx, fmaf(sM[k][1], fy, sM[k][2]));
        float q1 = fmaf(sM[k][4], fx, fmaf(sM[k][5], fy, sM[k][6]));
        float q2 = fmaf(sM[k][8], fx, fmaf(sM[k][9], fy, sM[k][10]));
        float m3 = sM[k][3], m7 = sM[k][7], m11 = sM[k][11];

        // precompute taps for this k, all 32 depths (fully unrolled: reg arrays)
        #pragma unroll
        for (int d = 0; d < NDT; ++d) {
            float depth = expf(fmaf(lr, (float)(dbase + d) * (1.f/63.f), lmn));
            float cam0 = fmaf(depth, q0, m3);
            float cam1 = fmaf(depth, q1, m7);
            float zraw = fmaf(depth, q2, m11);
            float z     = zraw + EPSF;
            float scale = (fabsf(zraw) > EPSF) ? (1.f / z) : 1.f;
            float x = cam0 * scale - 0.5f;
            float y = cam1 * scale - 0.5f;
            float x0f = floorf(x), y0f = floorf(y);
            float wx1 = x - x0f,  wy1 = y - y0f;
            float wx0 = 1.f - wx1, wy0 = 1.f - wy1;
            bool vx0 = (x0f >=  0.f) && (x0f <= 127.f);
            bool vx1 = (x0f >= -1.f) && (x0f <= 126.f);
            bool vy0 = (y0f >=  0.f) && (y0f <=  95.f);
            bool vy1 = (y0f >= -1.f) && (y0f <=  94.f);
            float zm = (z > 0.f) ? 1.f : 0.f;
            float w00 = (vx0 && vy0) ? wx0*wy0*zm : 0.f;
            float w01 = (vx1 && vy0) ? wx1*wy0*zm : 0.f;
            float w10 = (vx0 && vy1) ? wx0*wy1*zm : 0.f;
            float w11 = (vx1 && vy1) ? wx1*wy1*zm : 0.f;
            int ixb = (int)fminf(fmaxf(x0f, -1.f), 127.f);
            int iyb = (int)fminf(fmaxf(y0f, -1.f),  95.f);
            offs[d] = (unsigned)(iyb*ROWB + ixb*4 + BIAS);
            wA[d] = (f2bf(w01) << 16) | f2bf(w00);
            wB[d] = (f2bf(w11) << 16) | f2bf(w10);
        }

        const unsigned* kbase = srcC + (size_t)(b*KK + k)*NCH*HWSZ;

        for (int cc = 0; cc < NCH; ++cc) {
            __syncthreads();   // prior gathers done before overwrite
            // stage 49152B slice: 512 thr x 6 x uint4
            {
                const uint4* sp = reinterpret_cast<const uint4*>(kbase + (size_t)cc*HWSZ);
                #pragma unroll
                for (int i = 0; i < 6; ++i) {
                    uint4 v = sp[i*512 + tid];
                    int px0 = (i*512 + tid) * 4;
                    int row = px0 >> 7, col = px0 & 127;
                    char* wp = bpw + row*ROWB + col*4 + BIAS;
                    *reinterpret_cast<uint2*>(wp)     = make_uint2(v.x, v.y);
                    *reinterpret_cast<uint2*>(wp + 8) = make_uint2(v.z, v.w);
                }
            }
            __syncthreads();

            float2 cp = curP[(size_t)(b*NCH + cc)*HWSZ + p];
            float c0 = cp.x, c1 = cp.y;

            #pragma unroll
            for (int d = 0; d < NDT; ++d) {
                const char* tp = bp + offs[d];
                unsigned t00 = *reinterpret_cast<const unsigned*>(tp);
                unsigned t01 = *reinterpret_cast<const unsigned*>(tp + 4);
                unsigned t10 = *reinterpret_cast<const unsigned*>(tp + ROWB);
                unsigned t11 = *reinterpret_cast<const unsigned*>(tp + ROWB + 4);
                unsigned wa = wA[d], wb = wB[d];
                float p00 = fmaf(c1, bf_hi(t00), c0 * bf_lo(t00));
                float p01 = fmaf(c1, bf_hi(t01), c0 * bf_lo(t01));
                float p10 = fmaf(c1, bf_hi(t10), c0 * bf_lo(t10));
                float p11 = fmaf(c1, bf_hi(t11), c0 * bf_lo(t11));
                float s = acc[d];
                s = fmaf(bf_lo(wa), p00, s);
                s = fmaf(bf_hi(wa), p01, s);
                s = fmaf(bf_lo(wb), p10, s);
                s = fmaf(bf_hi(wb), p11, s);
                acc[d] = s;
            }
        }
    }

    #pragma unroll
    for (int d = 0; d < NDT; ++d)
        out[(size_t)(b*DD + dbase + d)*HWSZ + p] = acc[d];
}

// ---------- fallback (ws too small): round-1 style, known correct ----------
__global__ __launch_bounds__(256) void cv_fallback(
    const float* __restrict__ cur, const float* __restrict__ src,
    const float* __restrict__ Emat, const float* __restrict__ Kmat,
    const float* __restrict__ invK, const float* __restrict__ mnp,
    const float* __restrict__ mxp, float* __restrict__ out)
{
    int blk  = blockIdx.x;
    int tile = blk % (HWSZ/256);
    int bd   = blk / (HWSZ/256);
    int d    = bd % DD;
    int b    = bd / DD;
    __shared__ float sM[KK][12];
    __shared__ float sDepth;
    if (threadIdx.x < KK) {
        int k = threadIdx.x;
        const float* Km = Kmat + (size_t)(b*KK + k)*16;
        const float* Em = Emat + (size_t)(b*KK + k)*16;
        float P[3][4];
        #pragma unroll
        for (int i = 0; i < 3; ++i)
            #pragma unroll
            for (int jj = 0; jj < 4; ++jj) {
                float s = 0.f;
                #pragma unroll
                for (int l = 0; l < 4; ++l) s = fmaf(Km[i*4+l], Em[l*4+jj], s);
                P[i][jj] = s;
            }
        const float* iK = invK + (size_t)b*16;
        #pragma unroll
        for (int i = 0; i < 3; ++i) {
            #pragma unroll
            for (int jj = 0; jj < 3; ++jj) {
                float s = 0.f;
                #pragma unroll
                for (int l = 0; l < 3; ++l) s = fmaf(P[i][l], iK[l*4+jj], s);
                sM[k][i*4+jj] = s;
            }
            sM[k][i*4+3] = P[i][3];
        }
    }
    if (threadIdx.x == KK) {
        float mnb = mnp[b], mxb = mxp[b];
        sDepth = expf(logf(mnb) + logf(mxb/mnb) * ((float)d * (1.f/63.f)));
    }
    __syncthreads();
    int p  = tile*256 + threadIdx.x;
    float fx = (float)(p & (WW-1)) + 0.5f;
    float fy = (float)(p >> 7) + 0.5f;
    float depth = sDepth;
    float curv[CC];
    const float* curp = cur + (size_t)b*CC*HWSZ + p;
    #pragma unroll
    for (int c = 0; c < CC; ++c) curv[c] = curp[(size_t)c*HWSZ];
    float acc = 0.f;
    for (int k = 0; k < KK; ++k) {
        float q0 = fmaf(sM[k][0], fx, fmaf(sM[k][1], fy, sM[k][2]));
        float q1 = fmaf(sM[k][4], fx, fmaf(sM[k][5], fy, sM[k][6]));
        float q2 = fmaf(sM[k][8], fx, fmaf(sM[k][9], fy, sM[k][10]));
        float cam0 = fmaf(depth, q0, sM[k][3]);
        float cam1 = fmaf(depth, q1, sM[k][7]);
        float zraw = fmaf(depth, q2, sM[k][11]);
        float z     = zraw + EPSF;
        float scale = (fabsf(zraw) > EPSF) ? (1.f / z) : 1.f;
        float x = cam0 * scale - 0.5f;
        float y = cam1 * scale - 0.5f;
        float x0f = floorf(x), y0f = floorf(y);
        float wx1 = x - x0f,  wy1 = y - y0f;
        float wx0 = 1.f - wx1, wy0 = 1.f - wy1;
        bool vx0 = (x0f >= 0.f)   && (x0f <= 127.f);
        bool vx1 = (x0f >= -1.f)  && (x0f <= 126.f);
        bool vy0 = (y0f >= 0.f)   && (y0f <= 95.f);
        bool vy1 = (y0f >= -1.f)  && (y0f <= 94.f);
        float zm = (z > 0.f) ? 1.f : 0.f;
        float w00 = (vx0 && vy0) ? wx0*wy0*zm : 0.f;
        float w01 = (vx1 && vy0) ? wx1*wy0*zm : 0.f;
        float w10 = (vx0 && vy1) ? wx0*wy1*zm : 0.f;
        float w11 = (vx1 && vy1) ? wx1*wy1*zm : 0.f;
        int ix0 = (int)fminf(fmaxf(x0f,       0.f), 127.f);
        int ix1 = (int)fminf(fmaxf(x0f + 1.f, 0.f), 127.f);
        int iy0 = (int)fminf(fmaxf(y0f,       0.f), 95.f);
        int iy1 = (int)fminf(fmaxf(y0f + 1.f, 0.f), 95.f);
        const float* sb = src + (size_t)(b*KK + k)*CC*HWSZ;
        int o0 = iy0*WW+ix0, o1 = iy0*WW+ix1, o2 = iy1*WW+ix0, o3 = iy1*WW+ix1;
        float a0=0.f,a1=0.f,a2=0.f,a3=0.f;
        #pragma unroll 8
        for (int c = 0; c < CC; ++c) {
            const float* sc = sb + (size_t)c*HWSZ;
            a0 = fmaf(curv[c], sc[o0], a0);
            a1 = fmaf(curv[c], sc[o1], a1);
            a2 = fmaf(curv[c], sc[o2], a2);
            a3 = fmaf(curv[c], sc[o3], a3);
        }
        acc += w00*a0 + w01*a1 + w10*a2 + w11*a3;
    }
    out[(size_t)(b*DD + d)*HWSZ + p] = acc;
}

extern "C" void kernel_launch(void* const* d_in, const int* in_sizes, int n_in,
                              void* d_out, int out_size, void* d_ws, size_t ws_size,
                              hipStream_t stream) {
    const float* cur   = (const float*)d_in[0];
    const float* srcf  = (const float*)d_in[1];
    const float* Emat  = (const float*)d_in[2];
    const float* Kmat  = (const float*)d_in[3];
    const float* invK  = (const float*)d_in[4];
    const float* mn    = (const float*)d_in[5];
    const float* mx    = (const float*)d_in[6];
    float* out = (float*)d_out;

    const size_t srcC_bytes = (size_t)BB*KK*NCH*HWSZ*4;   // 44 MB
    const size_t curP_bytes = (size_t)BB*NCH*HWSZ*8;      // 12.6 MB

    if (ws_size >= srcC_bytes + curP_bytes) {
        unsigned* srcC = (unsigned*)d_ws;
        float2* curP = (float2*)((char*)d_ws + srcC_bytes);
        int nsrc = BB*KK*NCH*HWSZ;
        int ncur = BB*NCH*HWSZ;
        pack_src2<<<dim3((nsrc + 255)/256), dim3(256), 0, stream>>>(srcf, srcC);
        pack_cur2<<<dim3((ncur + 255)/256), dim3(256), 0, stream>>>(cur, curP);
        cv_lds<<<dim3(BB*(HWSZ/PXT)), dim3(512), 0, stream>>>(curP, srcC, Emat, Kmat, invK, mn, mx, out);
    } else {
        cv_fallback<<<dim3(BB*DD*(HWSZ/256)), dim3(256), 0, stream>>>(cur, srcf, Emat, Kmat, invK, mn, mx, out);
    }
}

// Round 7
// 946.685 us; speedup vs baseline: 2.5026x; 1.0292x over previous
//
#include <hip/hip_runtime.h>
#include <math.h>

#define HH 96
#define WW 128
#define DD 64
#define BB 8
#define KK 7
#define CC 32
#define HWSZ (HH*WW)
#define EPSF 1e-8f
#define NCH 16               // channel-pair chunks (2 f16 ch per u32)
#define NDT 16               // depths per thread
#define PXT 256              // pixels per block tile
#define ROWB 520             // LDS row stride bytes (130 px * 4B)
#define BIAS 528             // pad before slice (covers iyb=-1, ixb=-1)
#define BUFB (BIAS + HH*ROWB + 528)    // 50976 bytes
#define BUFW (BUFB/4)

typedef _Float16 h2 __attribute__((ext_vector_type(2)));

static __device__ __forceinline__ float bf_lo(unsigned u){ return __uint_as_float(u << 16); }
static __device__ __forceinline__ float bf_hi(unsigned u){ return __uint_as_float(u & 0xffff0000u); }
static __device__ __forceinline__ unsigned f2bf(float f){
    unsigned u = __float_as_uint(f);
    return (u + 0x7fffu + ((u >> 16) & 1u)) >> 16;   // RNE
}
static __device__ __forceinline__ unsigned packh2(float a, float b){
    unsigned short ha = __builtin_bit_cast(unsigned short, (_Float16)a);
    unsigned short hb = __builtin_bit_cast(unsigned short, (_Float16)b);
    return ((unsigned)hb << 16) | ha;
}
// dot product of two f16 pairs, f32 result
static __device__ __forceinline__ float dot2h(unsigned a, unsigned b){
#if __has_builtin(__builtin_amdgcn_fdot2)
    return __builtin_amdgcn_fdot2(__builtin_bit_cast(h2, a), __builtin_bit_cast(h2, b), 0.f, false);
#else
    h2 ha = __builtin_bit_cast(h2, a), hb = __builtin_bit_cast(h2, b);
    return (float)ha.x * (float)hb.x + (float)ha.y * (float)hb.y;
#endif
}

// ---- pack src: (B*K, C, HW) f32 -> (B*K, 16, HW) u32 of 2 f16 ch ----
__global__ __launch_bounds__(256) void pack_src2(const float* __restrict__ in,
                                                 unsigned* __restrict__ outP)
{
    int gid = blockIdx.x * 256 + threadIdx.x;
    int px  = gid % HWSZ;
    int rest = gid / HWSZ;
    int cc  = rest % NCH;
    int v   = rest / NCH;
    if (v >= BB*KK) return;
    const float* ip = in + (size_t)(v*CC + 2*cc)*HWSZ + px;
    outP[(size_t)(v*NCH + cc)*HWSZ + px] = packh2(ip[0], ip[HWSZ]);
}

// ---- pack cur: (B, C, HW) f32 -> (B, 16, HW) u32 of 2 f16 ch ----
__global__ __launch_bounds__(256) void pack_cur2(const float* __restrict__ in,
                                                 unsigned* __restrict__ outP)
{
    int gid = blockIdx.x * 256 + threadIdx.x;
    int px  = gid % HWSZ;
    int rest = gid / HWSZ;
    int cc  = rest % NCH;
    int b   = rest / NCH;
    if (b >= BB) return;
    const float* ip = in + (size_t)(b*CC + 2*cc)*HWSZ + px;
    outP[(size_t)(b*NCH + cc)*HWSZ + px] = packh2(ip[0], ip[HWSZ]);
}

// ---- main: LDS-staged, f16 dot2, depth-split blocks ----
__global__ __launch_bounds__(512, 2) void cv_lds(
    const unsigned* __restrict__ curPh,  // (B,16,HW) u32 (2 f16)
    const unsigned* __restrict__ srcC,   // (B,K,16,HW) u32 (2 f16)
    const float* __restrict__ Emat,
    const float* __restrict__ Kmat,
    const float* __restrict__ invK,
    const float* __restrict__ mnp,
    const float* __restrict__ mxp,
    float* __restrict__ out)
{
    __shared__ unsigned sbuf[BUFW];
    __shared__ float sM[KK][12];

    // blk = b + 8*(dhalf + 2*tile): b pins XCD; paired dhalf blocks are
    // dispatch-adjacent on the same XCD -> staging reads shared via L2.
    int blk   = blockIdx.x;
    int b     = blk & 7;
    int r     = blk >> 3;
    int dhalf = r & 1;
    int tile  = r >> 1;
    int tid   = threadIdx.x;

    for (int i = tid; i < BUFW; i += 512) sbuf[i] = 0;

    if (tid < KK) {
        int k = tid;
        const float* Km = Kmat + (size_t)(b*KK + k)*16;
        const float* Em = Emat + (size_t)(b*KK + k)*16;
        float P[3][4];
        #pragma unroll
        for (int i = 0; i < 3; ++i)
            #pragma unroll
            for (int jj = 0; jj < 4; ++jj) {
                float s = 0.f;
                #pragma unroll
                for (int l = 0; l < 4; ++l) s = fmaf(Km[i*4+l], Em[l*4+jj], s);
                P[i][jj] = s;
            }
        const float* iK = invK + (size_t)b*16;
        #pragma unroll
        for (int i = 0; i < 3; ++i) {
            #pragma unroll
            for (int jj = 0; jj < 3; ++jj) {
                float s = 0.f;
                #pragma unroll
                for (int l = 0; l < 3; ++l) s = fmaf(P[i][l], iK[l*4+jj], s);
                sM[k][i*4+jj] = s;
            }
            sM[k][i*4+3] = P[i][3];
        }
    }
    __syncthreads();

    int p     = tile*PXT + (tid & 255);
    int dg    = tid >> 8;                 // 0 or 1
    int dbase = dhalf*32 + dg*NDT;
    float fx = (float)(p & (WW-1)) + 0.5f;
    float fy = (float)(p >> 7) + 0.5f;

    float mnb = mnp[b];
    float lmn = logf(mnb);
    float lr  = logf(mxp[b] / mnb);

    // current-frame f16 channel pairs, resident for the whole block
    unsigned curp[NCH];
    #pragma unroll
    for (int cc = 0; cc < NCH; ++cc)
        curp[cc] = curPh[(size_t)(b*NCH + cc)*HWSZ + p];

    float acc[NDT];
    #pragma unroll
    for (int d = 0; d < NDT; ++d) acc[d] = 0.f;

    unsigned offs[NDT], wA[NDT], wB[NDT];
    const char* bp = (const char*)sbuf;
    char* bpw = (char*)sbuf;

    for (int k = 0; k < KK; ++k) {
        float q0 = fmaf(sM[k][0], fx, fmaf(sM[k][1], fy, sM[k][2]));
        float q1 = fmaf(sM[k][4], fx, fmaf(sM[k][5], fy, sM[k][6]));
        float q2 = fmaf(sM[k][8], fx, fmaf(sM[k][9], fy, sM[k][10]));
        float m3 = sM[k][3], m7 = sM[k][7], m11 = sM[k][11];

        #pragma unroll
        for (int d = 0; d < NDT; ++d) {
            float depth = expf(fmaf(lr, (float)(dbase + d) * (1.f/63.f), lmn));
            float cam0 = fmaf(depth, q0, m3);
            float cam1 = fmaf(depth, q1, m7);
            float zraw = fmaf(depth, q2, m11);
            float z     = zraw + EPSF;
            float scale = (fabsf(zraw) > EPSF) ? (1.f / z) : 1.f;
            float x = cam0 * scale - 0.5f;
            float y = cam1 * scale - 0.5f;
            float x0f = floorf(x), y0f = floorf(y);
            float wx1 = x - x0f,  wy1 = y - y0f;
            float wx0 = 1.f - wx1, wy0 = 1.f - wy1;
            bool vx0 = (x0f >=  0.f) && (x0f <= 127.f);
            bool vx1 = (x0f >= -1.f) && (x0f <= 126.f);
            bool vy0 = (y0f >=  0.f) && (y0f <=  95.f);
            bool vy1 = (y0f >= -1.f) && (y0f <=  94.f);
            float zm = (z > 0.f) ? 1.f : 0.f;
            float w00 = (vx0 && vy0) ? wx0*wy0*zm : 0.f;
            float w01 = (vx1 && vy0) ? wx1*wy0*zm : 0.f;
            float w10 = (vx0 && vy1) ? wx0*wy1*zm : 0.f;
            float w11 = (vx1 && vy1) ? wx1*wy1*zm : 0.f;
            int ixb = (int)fminf(fmaxf(x0f, -1.f), 127.f);
            int iyb = (int)fminf(fmaxf(y0f, -1.f),  95.f);
            offs[d] = (unsigned)(iyb*ROWB + ixb*4 + BIAS);
            wA[d] = (f2bf(w01) << 16) | f2bf(w00);
            wB[d] = (f2bf(w11) << 16) | f2bf(w10);
        }

        const unsigned* kbase = srcC + (size_t)(b*KK + k)*NCH*HWSZ;

        for (int cc = 0; cc < NCH; ++cc) {
            __syncthreads();
            {
                const uint4* sp = reinterpret_cast<const uint4*>(kbase + (size_t)cc*HWSZ);
                #pragma unroll
                for (int i = 0; i < 6; ++i) {
                    uint4 v = sp[i*512 + tid];
                    int px0 = (i*512 + tid) * 4;
                    int row = px0 >> 7, col = px0 & 127;
                    char* wp = bpw + row*ROWB + col*4 + BIAS;
                    *reinterpret_cast<uint2*>(wp)     = make_uint2(v.x, v.y);
                    *reinterpret_cast<uint2*>(wp + 8) = make_uint2(v.z, v.w);
                }
            }
            __syncthreads();

            unsigned cp = curp[cc];

            #pragma unroll
            for (int d = 0; d < NDT; ++d) {
                const char* tp = bp + offs[d];
                unsigned t00 = *reinterpret_cast<const unsigned*>(tp);
                unsigned t01 = *reinterpret_cast<const unsigned*>(tp + 4);
                unsigned t10 = *reinterpret_cast<const unsigned*>(tp + ROWB);
                unsigned t11 = *reinterpret_cast<const unsigned*>(tp + ROWB + 4);
                float td00 = dot2h(t00, cp);
                float td01 = dot2h(t01, cp);
                float td10 = dot2h(t10, cp);
                float td11 = dot2h(t11, cp);
                unsigned wa = wA[d], wb = wB[d];
                float s = acc[d];
                s = fmaf(bf_lo(wa), td00, s);
                s = fmaf(bf_hi(wa), td01, s);
                s = fmaf(bf_lo(wb), td10, s);
                s = fmaf(bf_hi(wb), td11, s);
                acc[d] = s;
            }
        }
    }

    #pragma unroll
    for (int d = 0; d < NDT; ++d)
        out[(size_t)(b*DD + dbase + d)*HWSZ + p] = acc[d];
}

// ---------- fallback (ws too small): round-1 style, known correct ----------
__global__ __launch_bounds__(256) void cv_fallback(
    const float* __restrict__ cur, const float* __restrict__ src,
    const float* __restrict__ Emat, const float* __restrict__ Kmat,
    const float* __restrict__ invK, const float* __restrict__ mnp,
    const float* __restrict__ mxp, float* __restrict__ out)
{
    int blk  = blockIdx.x;
    int tile = blk % (HWSZ/256);
    int bd   = blk / (HWSZ/256);
    int d    = bd % DD;
    int b    = bd / DD;
    __shared__ float sM[KK][12];
    __shared__ float sDepth;
    if (threadIdx.x < KK) {
        int k = threadIdx.x;
        const float* Km = Kmat + (size_t)(b*KK + k)*16;
        const float* Em = Emat + (size_t)(b*KK + k)*16;
        float P[3][4];
        #pragma unroll
        for (int i = 0; i < 3; ++i)
            #pragma unroll
            for (int jj = 0; jj < 4; ++jj) {
                float s = 0.f;
                #pragma unroll
                for (int l = 0; l < 4; ++l) s = fmaf(Km[i*4+l], Em[l*4+jj], s);
                P[i][jj] = s;
            }
        const float* iK = invK + (size_t)b*16;
        #pragma unroll
        for (int i = 0; i < 3; ++i) {
            #pragma unroll
            for (int jj = 0; jj < 3; ++jj) {
                float s = 0.f;
                #pragma unroll
                for (int l = 0; l < 3; ++l) s = fmaf(P[i][l], iK[l*4+jj], s);
                sM[k][i*4+jj] = s;
            }
            sM[k][i*4+3] = P[i][3];
        }
    }
    if (threadIdx.x == KK) {
        float mnb = mnp[b], mxb = mxp[b];
        sDepth = expf(logf(mnb) + logf(mxb/mnb) * ((float)d * (1.f/63.f)));
    }
    __syncthreads();
    int p  = tile*256 + threadIdx.x;
    float fx = (float)(p & (WW-1)) + 0.5f;
    float fy = (float)(p >> 7) + 0.5f;
    float depth = sDepth;
    float curv[CC];
    const float* curp = cur + (size_t)b*CC*HWSZ + p;
    #pragma unroll
    for (int c = 0; c < CC; ++c) curv[c] = curp[(size_t)c*HWSZ];
    float acc = 0.f;
    for (int k = 0; k < KK; ++k) {
        float q0 = fmaf(sM[k][0], fx, fmaf(sM[k][1], fy, sM[k][2]));
        float q1 = fmaf(sM[k][4], fx, fmaf(sM[k][5], fy, sM[k][6]));
        float q2 = fmaf(sM[k][8], fx, fmaf(sM[k][9], fy, sM[k][10]));
        float cam0 = fmaf(depth, q0, sM[k][3]);
        float cam1 = fmaf(depth, q1, sM[k][7]);
        float zraw = fmaf(depth, q2, sM[k][11]);
        float z     = zraw + EPSF;
        float scale = (fabsf(zraw) > EPSF) ? (1.f / z) : 1.f;
        float x = cam0 * scale - 0.5f;
        float y = cam1 * scale - 0.5f;
        float x0f = floorf(x), y0f = floorf(y);
        float wx1 = x - x0f,  wy1 = y - y0f;
        float wx0 = 1.f - wx1, wy0 = 1.f - wy1;
        bool vx0 = (x0f >= 0.f)   && (x0f <= 127.f);
        bool vx1 = (x0f >= -1.f)  && (x0f <= 126.f);
        bool vy0 = (y0f >= 0.f)   && (y0f <= 95.f);
        bool vy1 = (y0f >= -1.f)  && (y0f <= 94.f);
        float zm = (z > 0.f) ? 1.f : 0.f;
        float w00 = (vx0 && vy0) ? wx0*wy0*zm : 0.f;
        float w01 = (vx1 && vy0) ? wx1*wy0*zm : 0.f;
        float w10 = (vx0 && vy1) ? wx0*wy1*zm : 0.f;
        float w11 = (vx1 && vy1) ? wx1*wy1*zm : 0.f;
        int ix0 = (int)fminf(fmaxf(x0f,       0.f), 127.f);
        int ix1 = (int)fminf(fmaxf(x0f + 1.f, 0.f), 127.f);
        int iy0 = (int)fminf(fmaxf(y0f,       0.f), 95.f);
        int iy1 = (int)fminf(fmaxf(y0f + 1.f, 0.f), 95.f);
        const float* sb = src + (size_t)(b*KK + k)*CC*HWSZ;
        int o0 = iy0*WW+ix0, o1 = iy0*WW+ix1, o2 = iy1*WW+ix0, o3 = iy1*WW+ix1;
        float a0=0.f,a1=0.f,a2=0.f,a3=0.f;
        #pragma unroll 8
        for (int c = 0; c < CC; ++c) {
            const float* sc = sb + (size_t)c*HWSZ;
            a0 = fmaf(curv[c], sc[o0], a0);
            a1 = fmaf(curv[c], sc[o1], a1);
            a2 = fmaf(curv[c], sc[o2], a2);
            a3 = fmaf(curv[c], sc[o3], a3);
        }
        acc += w00*a0 + w01*a1 + w10*a2 + w11*a3;
    }
    out[(size_t)(b*DD + d)*HWSZ + p] = acc;
}

extern "C" void kernel_launch(void* const* d_in, const int* in_sizes, int n_in,
                              void* d_out, int out_size, void* d_ws, size_t ws_size,
                              hipStream_t stream) {
    const float* cur   = (const float*)d_in[0];
    const float* srcf  = (const float*)d_in[1];
    const float* Emat  = (const float*)d_in[2];
    const float* Kmat  = (const float*)d_in[3];
    const float* invK  = (const float*)d_in[4];
    const float* mn    = (const float*)d_in[5];
    const float* mx    = (const float*)d_in[6];
    float* out = (float*)d_out;

    const size_t srcC_bytes = (size_t)BB*KK*NCH*HWSZ*4;   // 44 MB
    const size_t curP_bytes = (size_t)BB*NCH*HWSZ*4;      // 6.3 MB

    if (ws_size >= srcC_bytes + curP_bytes) {
        unsigned* srcC = (unsigned*)d_ws;
        unsigned* curP = (unsigned*)((char*)d_ws + srcC_bytes);
        int nsrc = BB*KK*NCH*HWSZ;
        int ncur = BB*NCH*HWSZ;
        pack_src2<<<dim3((nsrc + 255)/256), dim3(256), 0, stream>>>(srcf, srcC);
        pack_cur2<<<dim3((ncur + 255)/256), dim3(256), 0, stream>>>(cur, curP);
        cv_lds<<<dim3(BB*(HWSZ/PXT)*2), dim3(512), 0, stream>>>(curP, srcC, Emat, Kmat, invK, mn, mx, out);
    } else {
        cv_fallback<<<dim3(BB*DD*(HWSZ/256)), dim3(256), 0, stream>>>(cur, srcf, Emat, Kmat, invK, mn, mx, out);
    }
}